// Round 14
// baseline (178.661 us; speedup 1.0000x reference)
//
#include <hip/hip_runtime.h>

// Problem constants (B=2, T=2048, D=1024, H=16, hd=64)
#define T_SEQ 2048
#define DMODEL 1024
#define NH 16
#define HD 64

typedef unsigned short u16;
typedef short s16;
typedef __attribute__((ext_vector_type(8))) unsigned short u16x8;
typedef __attribute__((ext_vector_type(4))) unsigned short u16x4;
typedef __attribute__((ext_vector_type(8))) short bf16x8;   // MFMA A/B frag
typedef __attribute__((ext_vector_type(4))) float f32x4;    // MFMA C/D frag

__device__ __forceinline__ u16 f2bf(float f) {              // RNE float->bf16 bits
    union { float f; unsigned u; } v; v.f = f;
    unsigned r = v.u + 0x7fffu + ((v.u >> 16) & 1u);
    return (u16)(r >> 16);
}

// Async global->LDS 16B copy (wave-uniform LDS base + lane*16 via linear map).
// void* signature: dtype-irrelevant, builtin takes address-space pointers.
__device__ __forceinline__ void gl_lds16(const void* g, void* l) {
    __builtin_amdgcn_global_load_lds(
        (const __attribute__((address_space(1))) unsigned int*)g,
        (__attribute__((address_space(3))) unsigned int*)l, 16, 0, 0);
}

// ---------------------------------------------------------------------------
// Elementwise fp32 -> bf16 convert (for x). 4 elements/thread.
// ---------------------------------------------------------------------------
__global__ __launch_bounds__(256) void convert_kernel(
    const float* __restrict__ in, u16* __restrict__ out, int n)
{
    int idx = (blockIdx.x * 256 + threadIdx.x) * 4;
    if (idx < n) {
        float4 v = *reinterpret_cast<const float4*>(&in[idx]);
        u16x4 o;
        o.x = f2bf(v.x); o.y = f2bf(v.y); o.z = f2bf(v.z); o.w = f2bf(v.w);
        *reinterpret_cast<u16x4*>(&out[idx]) = o;
    }
}

// ---------------------------------------------------------------------------
// in [K][N] fp32 -> out [N][K] bf16 (transpose + convert). 64x64 LDS tiles.
// ---------------------------------------------------------------------------
__global__ __launch_bounds__(256) void transpose_convert_kernel(
    const float* __restrict__ in, u16* __restrict__ out, int K, int N)
{
    __shared__ u16 tile[64][65];          // [n][k], +1 pad
    const int tid = threadIdx.x;
    const int k0 = blockIdx.y * 64, n0 = blockIdx.x * 64;
    const int r  = tid >> 2;              // 0..63
    const int c4 = (tid & 3) * 16;        // 0/16/32/48
    #pragma unroll
    for (int i = 0; i < 4; ++i) {
        float4 v = *reinterpret_cast<const float4*>(&in[(size_t)(k0 + r) * N + n0 + c4 + i * 4]);
        tile[c4 + i*4 + 0][r] = f2bf(v.x);
        tile[c4 + i*4 + 1][r] = f2bf(v.y);
        tile[c4 + i*4 + 2][r] = f2bf(v.z);
        tile[c4 + i*4 + 3][r] = f2bf(v.w);
    }
    __syncthreads();
    u16x8 o0, o1;
    #pragma unroll
    for (int i = 0; i < 8; ++i) o0[i] = tile[r][c4 + i];
    #pragma unroll
    for (int i = 0; i < 8; ++i) o1[i] = tile[r][c4 + 8 + i];
    *reinterpret_cast<u16x8*>(&out[(size_t)(n0 + r) * K + k0 + c4])     = o0;
    *reinterpret_cast<u16x8*>(&out[(size_t)(n0 + r) * K + k0 + c4 + 8]) = o1;
}

// ---------------------------------------------------------------------------
// MFMA GEMM: C[M,N] = A[M,K](bf16) @ BT[N,K](bf16)^T + bias.
// BM=128, BK=64, 256 threads (4 waves 2x2), 16x16x32 MFMA.
// Round-11 structure (BK=64, source-side chunk swizzle, gl_lds 16B) +
// XCD-aware bijective block swizzle (nwg%8==0) for per-XCD L2 reuse.
// ---------------------------------------------------------------------------
template<int BM, int BN, bool OUT_BF16>
__global__ __launch_bounds__(256) void gemm_mfma_kernel(
    const u16* __restrict__ A, const u16* __restrict__ BT,
    const float* __restrict__ bias,
    float* __restrict__ C, u16* __restrict__ Cb,
    int M, int N, int K)
{
    constexpr int BK = 64;                 // elems; 8 chunks of 8 bf16 per row
    __shared__ __align__(16) u16 As[BM * BK];
    __shared__ __align__(16) u16 Bs[BN * BK];

    const int tid  = threadIdx.x;
    const int wave = tid >> 6, lane = tid & 63;

    // XCD swizzle: contiguous block-chunk per XCD (bijective since nwg%8==0)
    const int nwg = gridDim.x * gridDim.y;
    const int d   = blockIdx.y * gridDim.x + blockIdx.x;
    const int o   = (d & 7) * (nwg >> 3) + (d >> 3);
    const int m0 = (o / gridDim.x) * BM, n0 = (o % gridDim.x) * BN;

    constexpr int WM = BM / 2, WN = BN / 2;
    constexpr int MF = WM / 16, NF = WN / 16;
    const int wm = (wave >> 1) * WM, wn = (wave & 1) * WN;
    const int l15 = lane & 15, l4 = lane >> 4;
    const int l7  = l15 & 7;               // row&7 for all frag rows

    f32x4 acc[MF][NF];
    #pragma unroll
    for (int nf = 0; nf < NF; ++nf) {
        const float bv = bias[n0 + wn + nf * 16 + l15];
        #pragma unroll
        for (int mf = 0; mf < MF; ++mf)
            acc[mf][nf] = (f32x4){bv, bv, bv, bv};
    }

    constexpr int ALOADS = BM / 32;        // 16B chunks per thread for A tile
    constexpr int BLOADS = BN / 32;

    for (int k0 = 0; k0 < K; k0 += BK) {
        __syncthreads();   // previous iteration's frag reads complete
        #pragma unroll
        for (int i = 0; i < ALOADS; ++i) {
            const int p = tid + i * 256;   // linear chunk id
            const int r = p >> 3, c = p & 7;
            gl_lds16(&A[(size_t)(m0 + r) * K + k0 + ((c ^ (r & 7)) * 8)], &As[(size_t)p * 8]);
        }
        #pragma unroll
        for (int i = 0; i < BLOADS; ++i) {
            const int p = tid + i * 256;
            const int r = p >> 3, c = p & 7;
            gl_lds16(&BT[(size_t)(n0 + r) * K + k0 + ((c ^ (r & 7)) * 8)], &Bs[(size_t)p * 8]);
        }
        __syncthreads();   // drains vmcnt -> LDS valid

        bf16x8 af[MF][2], bfr[NF][2];
        #pragma unroll
        for (int kk = 0; kk < 2; ++kk) {
            const int cc = kk * 4 + l4;    // chunk col 0..7
            const int cs = cc ^ l7;        // swizzled chunk col
            #pragma unroll
            for (int mf = 0; mf < MF; ++mf)
                af[mf][kk] = *reinterpret_cast<const bf16x8*>(
                    &As[(size_t)((wm + mf * 16 + l15) * 8 + cs) * 8]);
            #pragma unroll
            for (int nf = 0; nf < NF; ++nf)
                bfr[nf][kk] = *reinterpret_cast<const bf16x8*>(
                    &Bs[(size_t)((wn + nf * 16 + l15) * 8 + cs) * 8]);
        }
        #pragma unroll
        for (int kk = 0; kk < 2; ++kk)
            #pragma unroll
            for (int mf = 0; mf < MF; ++mf)
                #pragma unroll
                for (int nf = 0; nf < NF; ++nf)
                    acc[mf][nf] = __builtin_amdgcn_mfma_f32_16x16x32_bf16(
                        af[mf][kk], bfr[nf][kk], acc[mf][nf], 0, 0, 0);
    }

    #pragma unroll
    for (int mf = 0; mf < MF; ++mf)
        #pragma unroll
        for (int nf = 0; nf < NF; ++nf) {
            const int col = n0 + wn + nf * 16 + l15;
            #pragma unroll
            for (int r = 0; r < 4; ++r) {
                const int row = m0 + wm + mf * 16 + l4 * 4 + r;
                if constexpr (OUT_BF16) Cb[(size_t)row * N + col] = f2bf(acc[mf][nf][r]);
                else                    C [(size_t)row * N + col] = acc[mf][nf][r];
            }
        }
}

// ---------------------------------------------------------------------------
// MFMA sliding-window attention — pipelined.
// Double-buffered Ks (gl_lds, source-swizzled) and Vt (reg-staged, chunk
// swizzle); single Ps. 2 barriers/chunk (was 3); chunk c+1's K-DMA and
// V-loads issue before QK^T(c) so their latency hides under QK+softmax.
// Race audit: Ps write(c) -> bar1 -> Ps read(c) -> bar2 -> Ps write(c+1);
// Vt[cur^1] write (after bar1(c)) vs last reads (PV(c-1), before bar2(c-1));
// Ks[cur^1] DMA drains at bar1(c), read from QK(c+1).
// ---------------------------------------------------------------------------
__global__ __launch_bounds__(256, 4) void swa_mfma_kernel(
    const u16* __restrict__ qkv, u16* __restrict__ out,
    const int* __restrict__ wptr)
{
    const int window = *wptr;
    const int qt = blockIdx.x;
    const int bh = blockIdx.y;
    const int b  = bh >> 4;
    const int h  = bh & (NH - 1);

    const int tid  = threadIdx.x;
    const int wave = tid >> 6, lane = tid & 63;
    const int l15  = lane & 15, l4 = lane >> 4;
    const int hoff = h * HD;

    __shared__ __align__(16) s16 Ks[2][64 * 64];   // [key][hd], src-swizzled
    __shared__ __align__(16) s16 Vt[2][64 * 64];   // [hd][key], chunk swizzle
    __shared__ __align__(16) s16 Ps[64 * 64];      // [q][key],  row swizzle

    auto swz = [](int row, int col) { return (row * 64 + col) ^ ((row & 7) << 3); };
    auto vtx = [](int d, int k) { return d * 64 + (((k >> 3) ^ (d >> 3)) & 7) * 8 + (k & 7); };

    const size_t qgrow = (size_t)(b * T_SEQ + qt * 64 + wave * 16 + l15) * (3 * DMODEL) + hoff;
    const bf16x8 qf0 = *reinterpret_cast<const bf16x8*>(&qkv[qgrow + l4 * 8]);
    const bf16x8 qf1 = *reinterpret_cast<const bf16x8*>(&qkv[qgrow + 32 + l4 * 8]);

    f32x4 oacc[4];
    #pragma unroll
    for (int nf = 0; nf < 4; ++nf) oacc[nf] = (f32x4){0.f, 0.f, 0.f, 0.f};
    float m[4] = {-1e30f, -1e30f, -1e30f, -1e30f};
    float l[4] = {0.f, 0.f, 0.f, 0.f};

    const int lo = qt * 64 - window;
    const int cstart = (lo <= 0) ? 0 : (lo >> 6);

    // staging maps: linear chunk p -> row p>>3, chunk col p&7 (2 per thread)
    const int kr = tid >> 3;               // 0..31
    const int kc = (tid & 7) * 8;          // 0..56

    // K: gl_lds with source-side chunk XOR (linear dest = involution on read)
    auto issueK = [&](int c, int buf) {
        #pragma unroll
        for (int pass = 0; pass < 2; ++pass) {
            const int p = tid + pass * 256;
            const int r = p >> 3, cc = p & 7;
            const size_t g = (size_t)(b * T_SEQ + c * 64 + r) * (3 * DMODEL)
                             + DMODEL + hoff + ((cc ^ (r & 7)) * 8);
            gl_lds16(&qkv[g], &Ks[buf][(size_t)p * 8]);
        }
    };
    auto loadV = [&](int c, bf16x8& v0, bf16x8& v1) {
        const size_t g0 = (size_t)(b * T_SEQ + c * 64 + kr) * (3 * DMODEL) + 2 * DMODEL + hoff + kc;
        const size_t g1 = (size_t)(b * T_SEQ + c * 64 + kr + 32) * (3 * DMODEL) + 2 * DMODEL + hoff + kc;
        v0 = *reinterpret_cast<const bf16x8*>(&qkv[g0]);
        v1 = *reinterpret_cast<const bf16x8*>(&qkv[g1]);
    };
    auto writeV = [&](const bf16x8& v0, const bf16x8& v1, int buf) {
        #pragma unroll
        for (int i = 0; i < 8; ++i) Vt[buf][vtx(kc + i, kr)]      = v0[i];
        #pragma unroll
        for (int i = 0; i < 8; ++i) Vt[buf][vtx(kc + i, kr + 32)] = v1[i];
    };

    // prologue: fill buffer 0 with chunk cstart
    {
        issueK(cstart, 0);
        bf16x8 v0, v1;
        loadV(cstart, v0, v1);
        __syncthreads();                   // K DMA drained & visible
        writeV(v0, v1, 0);
        __syncthreads();                   // Vt visible
    }

    int cur = 0;
    for (int c = cstart; c <= qt; ++c) {
        const int j0 = c * 64;
        bf16x8 nv0, nv1;
        const bool pre = (c < qt);
        if (pre) { issueK(c + 1, cur ^ 1); loadV(c + 1, nv0, nv1); }

        // ---- S = Q @ K^T ----
        f32x4 sacc[4];
        #pragma unroll
        for (int nf = 0; nf < 4; ++nf) sacc[nf] = (f32x4){0.f, 0.f, 0.f, 0.f};
        #pragma unroll
        for (int nf = 0; nf < 4; ++nf) {
            const bf16x8 kf0 = *reinterpret_cast<const bf16x8*>(&Ks[cur][swz(nf * 16 + l15, l4 * 8)]);
            const bf16x8 kf1 = *reinterpret_cast<const bf16x8*>(&Ks[cur][swz(nf * 16 + l15, 32 + l4 * 8)]);
            sacc[nf] = __builtin_amdgcn_mfma_f32_16x16x32_bf16(qf0, kf0, sacc[nf], 0, 0, 0);
            sacc[nf] = __builtin_amdgcn_mfma_f32_16x16x32_bf16(qf1, kf1, sacc[nf], 0, 0, 0);
        }

        // ---- online softmax ----
        float p[4][4];
        #pragma unroll
        for (int r = 0; r < 4; ++r) {
            const int iq = qt * 64 + wave * 16 + l4 * 4 + r;
            float rmax = -1e30f;
            #pragma unroll
            for (int nf = 0; nf < 4; ++nf) {
                const int diff = iq - (j0 + nf * 16 + l15);
                const bool valid = (diff >= 0) && (diff <= window);
                const float s = valid ? sacc[nf][r] * 0.125f : -1e30f;
                p[r][nf] = s;
                rmax = fmaxf(rmax, s);
            }
            rmax = fmaxf(rmax, __shfl_xor(rmax, 1));
            rmax = fmaxf(rmax, __shfl_xor(rmax, 2));
            rmax = fmaxf(rmax, __shfl_xor(rmax, 4));
            rmax = fmaxf(rmax, __shfl_xor(rmax, 8));
            const float mn = fmaxf(m[r], rmax);
            const float rf = __expf(m[r] - mn);
            float rs = 0.f;
            #pragma unroll
            for (int nf = 0; nf < 4; ++nf) {
                const float e = __expf(p[r][nf] - mn);
                p[r][nf] = e;
                rs += e;
            }
            rs += __shfl_xor(rs, 1);
            rs += __shfl_xor(rs, 2);
            rs += __shfl_xor(rs, 4);
            rs += __shfl_xor(rs, 8);
            l[r] = l[r] * rf + rs;
            m[r] = mn;
            #pragma unroll
            for (int nf = 0; nf < 4; ++nf) oacc[nf][r] *= rf;
            #pragma unroll
            for (int nf = 0; nf < 4; ++nf)
                Ps[swz(wave * 16 + l4 * 4 + r, nf * 16 + l15)] = (s16)f2bf(p[r][nf]);
        }
        __syncthreads();   // bar1: Ps visible; drains K-DMA(c+1) (hidden under QK+softmax)

        // ---- O += P @ V ----
        #pragma unroll
        for (int ks = 0; ks < 2; ++ks) {
            const bf16x8 pa = *reinterpret_cast<const bf16x8*>(&Ps[swz(wave * 16 + l15, ks * 32 + l4 * 8)]);
            #pragma unroll
            for (int nf = 0; nf < 4; ++nf) {
                const bf16x8 vf = *reinterpret_cast<const bf16x8*>(&Vt[cur][vtx(nf * 16 + l15, ks * 32 + l4 * 8)]);
                oacc[nf] = __builtin_amdgcn_mfma_f32_16x16x32_bf16(pa, vf, oacc[nf], 0, 0, 0);
            }
        }
        if (pre) writeV(nv0, nv1, cur ^ 1);   // write-late (T14)
        __syncthreads();   // bar2: PV done (Ps free), Vt[cur^1] visible
        cur ^= 1;
    }

    // ---- epilogue: normalize, write bf16 ----
    #pragma unroll
    for (int r = 0; r < 4; ++r) {
        const float inv = 1.f / l[r];
        const size_t orow = (size_t)(b * T_SEQ + qt * 64 + wave * 16 + l4 * 4 + r) * DMODEL + hoff;
        #pragma unroll
        for (int nf = 0; nf < 4; ++nf)
            out[orow + nf * 16 + l15] = f2bf(oacc[nf][r] * inv);
    }
}

// ---------------------------------------------------------------------------
extern "C" void kernel_launch(void* const* d_in, const int* in_sizes, int n_in,
                              void* d_out, int out_size, void* d_ws, size_t ws_size,
                              hipStream_t stream) {
    (void)in_sizes; (void)n_in; (void)out_size; (void)ws_size;

    const float* x     = (const float*)d_in[0];   // [4096, 1024]
    const float* w_qkv = (const float*)d_in[1];   // [1024, 3072]
    const float* b_qkv = (const float*)d_in[2];   // [3072]
    const float* w_o   = (const float*)d_in[3];   // [1024, 1024]
    const float* b_o   = (const float*)d_in[4];   // [1024]
    const int*   wnd   = (const int*)d_in[5];

    const int M = 2 * T_SEQ;                      // 4096

    // ws layout (bytes): qkvb 24M | attb 8M | xb 8M | wqkvT 6M | woT 2M = 48 MB
    char* w = (char*)d_ws;
    u16* qkvb  = (u16*)(w);
    u16* attb  = (u16*)(w + 24u * 1024 * 1024);
    u16* xb    = (u16*)(w + 32u * 1024 * 1024);
    u16* wqkvT = (u16*)(w + 40u * 1024 * 1024);
    u16* woT   = (u16*)(w + 46u * 1024 * 1024);

    dim3 blk(256);

    // converts (independent)
    convert_kernel<<<dim3(M * DMODEL / 4 / 256), blk, 0, stream>>>(x, xb, M * DMODEL);
    transpose_convert_kernel<<<dim3(3 * DMODEL / 64, DMODEL / 64), blk, 0, stream>>>(
        w_qkv, wqkvT, DMODEL, 3 * DMODEL);
    transpose_convert_kernel<<<dim3(DMODEL / 64, DMODEL / 64), blk, 0, stream>>>(
        w_o, woT, DMODEL, DMODEL);

    // 1) qkv(bf16) = x @ w_qkv + b_qkv    (BK=64, swizzled gl_lds, XCD swizzle)
    gemm_mfma_kernel<128, 128, true><<<dim3(3 * DMODEL / 128, M / 128), blk, 0, stream>>>(
        xb, wqkvT, b_qkv, nullptr, qkvb, M, 3 * DMODEL, DMODEL);

    // 2) banded attention (MFMA, pipelined)
    swa_mfma_kernel<<<dim3(T_SEQ / 64, 2 * NH), blk, 0, stream>>>(qkvb, attb, wnd);

    // 3) out(fp32) = att @ w_o + b_o      (BN=64: 512 blocks = 2/CU)
    gemm_mfma_kernel<128, 64, false><<<dim3(DMODEL / 64, M / 128), blk, 0, stream>>>(
        attb, woT, b_o, (float*)d_out, nullptr, M, DMODEL, DMODEL);
}

// Round 15
// 165.125 us; speedup vs baseline: 1.0820x; 1.0820x over previous
//
#include <hip/hip_runtime.h>

// Problem constants (B=2, T=2048, D=1024, H=16, hd=64)
#define T_SEQ 2048
#define DMODEL 1024
#define NH 16
#define HD 64

typedef unsigned short u16;
typedef short s16;
typedef __attribute__((ext_vector_type(8))) unsigned short u16x8;
typedef __attribute__((ext_vector_type(4))) unsigned short u16x4;
typedef __attribute__((ext_vector_type(8))) short bf16x8;   // MFMA A/B frag
typedef __attribute__((ext_vector_type(4))) float f32x4;    // MFMA C/D frag

__device__ __forceinline__ u16 f2bf(float f) {              // RNE float->bf16 bits
    union { float f; unsigned u; } v; v.f = f;
    unsigned r = v.u + 0x7fffu + ((v.u >> 16) & 1u);
    return (u16)(r >> 16);
}

// Async global->LDS 16B copy (wave-uniform LDS base + lane*16 via linear map).
__device__ __forceinline__ void gl_lds16(const void* g, void* l) {
    __builtin_amdgcn_global_load_lds(
        (const __attribute__((address_space(1))) unsigned int*)g,
        (__attribute__((address_space(3))) unsigned int*)l, 16, 0, 0);
}

// ---------------------------------------------------------------------------
// Unified prep kernel (merges x-convert + both weight transposes -> 1 launch).
// Blocks [0,4096): x fp32->bf16. [4096,4864): w_qkv [K][3D]->[3D][K] bf16.
// [4864,5120): w_o [K][D]->[D][K] bf16.
// ---------------------------------------------------------------------------
#define XCONV_BLOCKS 4096
#define WQKV_BLOCKS  768    // (3D/64=48) x (D/64=16)
#define WO_BLOCKS    256    // (D/64=16)  x (D/64=16)

__global__ __launch_bounds__(256) void prep_kernel(
    const float* __restrict__ x,     u16* __restrict__ xb,
    const float* __restrict__ wqkv,  u16* __restrict__ wqkvT,
    const float* __restrict__ wo,    u16* __restrict__ woT)
{
    __shared__ u16 tile[64][65];
    const int tid = threadIdx.x;
    const int bid = blockIdx.x;

    if (bid < XCONV_BLOCKS) {                       // ---- x convert ----
        const int idx = (bid * 256 + tid) * 4;
        float4 v = *reinterpret_cast<const float4*>(&x[idx]);
        u16x4 o;
        o.x = f2bf(v.x); o.y = f2bf(v.y); o.z = f2bf(v.z); o.w = f2bf(v.w);
        *reinterpret_cast<u16x4*>(&xb[idx]) = o;
        return;
    }

    // ---- transpose-convert path ----
    const float* in; u16* out; int K, N, bx, by;
    if (bid < XCONV_BLOCKS + WQKV_BLOCKS) {
        const int bi = bid - XCONV_BLOCKS;
        in = wqkv; out = wqkvT; K = DMODEL; N = 3 * DMODEL;
        bx = bi % 48; by = bi / 48;
    } else {
        const int bi = bid - XCONV_BLOCKS - WQKV_BLOCKS;
        in = wo; out = woT; K = DMODEL; N = DMODEL;
        bx = bi % 16; by = bi / 16;
    }
    const int k0 = by * 64, n0 = bx * 64;
    const int r  = tid >> 2;
    const int c4 = (tid & 3) * 16;
    #pragma unroll
    for (int i = 0; i < 4; ++i) {
        float4 v = *reinterpret_cast<const float4*>(&in[(size_t)(k0 + r) * N + n0 + c4 + i * 4]);
        tile[c4 + i*4 + 0][r] = f2bf(v.x);
        tile[c4 + i*4 + 1][r] = f2bf(v.y);
        tile[c4 + i*4 + 2][r] = f2bf(v.z);
        tile[c4 + i*4 + 3][r] = f2bf(v.w);
    }
    __syncthreads();
    u16x8 o0, o1;
    #pragma unroll
    for (int i = 0; i < 8; ++i) o0[i] = tile[r][c4 + i];
    #pragma unroll
    for (int i = 0; i < 8; ++i) o1[i] = tile[r][c4 + 8 + i];
    *reinterpret_cast<u16x8*>(&out[(size_t)(n0 + r) * K + k0 + c4])     = o0;
    *reinterpret_cast<u16x8*>(&out[(size_t)(n0 + r) * K + k0 + c4 + 8]) = o1;
}

// ---------------------------------------------------------------------------
// MFMA GEMM — EXACT round-11 structure (165.3 µs config; XCD swizzle removed).
// BM=128, BK=64, 256 threads (4 waves 2x2), 16x16x32 MFMA, gl_lds 16B with
// source-side chunk swizzle + matching frag-read XOR.
// ---------------------------------------------------------------------------
template<int BM, int BN, bool OUT_BF16>
__global__ __launch_bounds__(256) void gemm_mfma_kernel(
    const u16* __restrict__ A, const u16* __restrict__ BT,
    const float* __restrict__ bias,
    float* __restrict__ C, u16* __restrict__ Cb,
    int M, int N, int K)
{
    constexpr int BK = 64;
    __shared__ __align__(16) u16 As[BM * BK];
    __shared__ __align__(16) u16 Bs[BN * BK];

    const int tid  = threadIdx.x;
    const int wave = tid >> 6, lane = tid & 63;
    const int m0 = blockIdx.y * BM, n0 = blockIdx.x * BN;

    constexpr int WM = BM / 2, WN = BN / 2;
    constexpr int MF = WM / 16, NF = WN / 16;
    const int wm = (wave >> 1) * WM, wn = (wave & 1) * WN;
    const int l15 = lane & 15, l4 = lane >> 4;
    const int l7  = l15 & 7;

    f32x4 acc[MF][NF];
    #pragma unroll
    for (int nf = 0; nf < NF; ++nf) {
        const float bv = bias[n0 + wn + nf * 16 + l15];
        #pragma unroll
        for (int mf = 0; mf < MF; ++mf)
            acc[mf][nf] = (f32x4){bv, bv, bv, bv};
    }

    constexpr int ALOADS = BM / 32;
    constexpr int BLOADS = BN / 32;

    for (int k0 = 0; k0 < K; k0 += BK) {
        __syncthreads();
        #pragma unroll
        for (int i = 0; i < ALOADS; ++i) {
            const int p = tid + i * 256;
            const int r = p >> 3, c = p & 7;
            gl_lds16(&A[(size_t)(m0 + r) * K + k0 + ((c ^ (r & 7)) * 8)], &As[(size_t)p * 8]);
        }
        #pragma unroll
        for (int i = 0; i < BLOADS; ++i) {
            const int p = tid + i * 256;
            const int r = p >> 3, c = p & 7;
            gl_lds16(&BT[(size_t)(n0 + r) * K + k0 + ((c ^ (r & 7)) * 8)], &Bs[(size_t)p * 8]);
        }
        __syncthreads();

        bf16x8 af[MF][2], bfr[NF][2];
        #pragma unroll
        for (int kk = 0; kk < 2; ++kk) {
            const int cc = kk * 4 + l4;
            const int cs = cc ^ l7;
            #pragma unroll
            for (int mf = 0; mf < MF; ++mf)
                af[mf][kk] = *reinterpret_cast<const bf16x8*>(
                    &As[(size_t)((wm + mf * 16 + l15) * 8 + cs) * 8]);
            #pragma unroll
            for (int nf = 0; nf < NF; ++nf)
                bfr[nf][kk] = *reinterpret_cast<const bf16x8*>(
                    &Bs[(size_t)((wn + nf * 16 + l15) * 8 + cs) * 8]);
        }
        #pragma unroll
        for (int kk = 0; kk < 2; ++kk)
            #pragma unroll
            for (int mf = 0; mf < MF; ++mf)
                #pragma unroll
                for (int nf = 0; nf < NF; ++nf)
                    acc[mf][nf] = __builtin_amdgcn_mfma_f32_16x16x32_bf16(
                        af[mf][kk], bfr[nf][kk], acc[mf][nf], 0, 0, 0);
    }

    #pragma unroll
    for (int mf = 0; mf < MF; ++mf)
        #pragma unroll
        for (int nf = 0; nf < NF; ++nf) {
            const int col = n0 + wn + nf * 16 + l15;
            #pragma unroll
            for (int r = 0; r < 4; ++r) {
                const int row = m0 + wm + mf * 16 + l4 * 4 + r;
                if constexpr (OUT_BF16) Cb[(size_t)row * N + col] = f2bf(acc[mf][nf][r]);
                else                    C [(size_t)row * N + col] = acc[mf][nf][r];
            }
        }
}

// ---------------------------------------------------------------------------
// MFMA sliding-window attention — QBLK=128, 512 threads (8 waves x 16 rows).
// Inner structure (3 barriers/chunk, reg-staged K/V, swz/vtx swizzles,
// QK frag geometry, online softmax) is byte-identical to the round-11
// kernel; only the tile width + per-wave chunk skip changed.
// Staging economics: 6 chunks serve 128 queries (was 5 per 64) -> ~40% less
// K/V re-staging and fewer barriers per query.
// Chunk-skip safety (window=256, q0 16-aligned, j0 64-aligned): a non-skipped
// chunk has >=1 valid key for EVERY query in the wave, so no all-masked row
// ever reaches the exp (proof: j0<=q0 from causal side since j0-q0 is a
// multiple of 16; j0 >= q0-304 from window side => j0+63 >= (q0+15)-256).
// ---------------------------------------------------------------------------
__global__ __launch_bounds__(512) void swa_mfma_kernel(
    const u16* __restrict__ qkv, u16* __restrict__ out,
    const int* __restrict__ wptr)
{
    const int window = *wptr;
    const int qt = blockIdx.x;             // 128-query tile
    const int bh = blockIdx.y;
    const int b  = bh >> 4;
    const int h  = bh & (NH - 1);

    const int tid  = threadIdx.x;
    const int wave = tid >> 6, lane = tid & 63;
    const int l15  = lane & 15, l4 = lane >> 4;
    const int hoff = h * HD;

    __shared__ __align__(16) s16 Ks[64 * 64];    // [key][hd], row swizzle
    __shared__ __align__(16) s16 Vt[64 * 64];    // [hd][key], chunk swizzle
    __shared__ __align__(16) s16 Ps[128 * 64];   // [q][key],  row swizzle

    auto swz = [](int row, int col) { return (row * 64 + col) ^ ((row & 7) << 3); };
    auto vtx = [](int d, int k) { return d * 64 + (((k >> 3) ^ (d >> 3)) & 7) * 8 + (k & 7); };

    // Q fragments: A-frag rows = qt*128 + wave*16 + l15
    const size_t qgrow = (size_t)(b * T_SEQ + qt * 128 + wave * 16 + l15) * (3 * DMODEL) + hoff;
    const bf16x8 qf0 = *reinterpret_cast<const bf16x8*>(&qkv[qgrow + l4 * 8]);
    const bf16x8 qf1 = *reinterpret_cast<const bf16x8*>(&qkv[qgrow + 32 + l4 * 8]);

    f32x4 oacc[4];
    #pragma unroll
    for (int nf = 0; nf < 4; ++nf) oacc[nf] = (f32x4){0.f, 0.f, 0.f, 0.f};
    float m[4] = {-1e30f, -1e30f, -1e30f, -1e30f};
    float l[4] = {0.f, 0.f, 0.f, 0.f};

    const int lo = qt * 128 - window;
    const int cstart = (lo <= 0) ? 0 : (lo >> 6);
    const int cend   = 2 * qt + 1;         // last causal chunk

    // loader map (512 thr, one pass): row kr 0..63, 8-col chunk kc
    const int kr = tid >> 3;
    const int kc = (tid & 7) * 8;

    const int q0 = qt * 128 + wave * 16;   // wave's first query

    for (int c = cstart; c <= cend; ++c) {
        const int j0 = c * 64;
        __syncthreads();                   // protect Ks/Vt while others read
        {
            const size_t g = (size_t)(b * T_SEQ + j0 + kr) * (3 * DMODEL) + DMODEL + hoff + kc;
            const bf16x8 kv8 = *reinterpret_cast<const bf16x8*>(&qkv[g]);
            const bf16x8 vv8 = *reinterpret_cast<const bf16x8*>(&qkv[g + DMODEL]);
            *reinterpret_cast<bf16x8*>(&Ks[swz(kr, kc)]) = kv8;
            #pragma unroll
            for (int i = 0; i < 8; ++i)
                Vt[vtx(kc + i, kr)] = vv8[i];
        }
        __syncthreads();

        // wave-uniform chunk skip (no lane divergence; barriers outside)
        const bool active = (j0 <= q0 + 15) && (j0 + 63 >= q0 - window);

        if (active) {
            // ---- S = Q @ K^T ----
            f32x4 sacc[4];
            #pragma unroll
            for (int nf = 0; nf < 4; ++nf) sacc[nf] = (f32x4){0.f, 0.f, 0.f, 0.f};
            #pragma unroll
            for (int nf = 0; nf < 4; ++nf) {
                const bf16x8 kf0 = *reinterpret_cast<const bf16x8*>(&Ks[swz(nf * 16 + l15, l4 * 8)]);
                const bf16x8 kf1 = *reinterpret_cast<const bf16x8*>(&Ks[swz(nf * 16 + l15, 32 + l4 * 8)]);
                sacc[nf] = __builtin_amdgcn_mfma_f32_16x16x32_bf16(qf0, kf0, sacc[nf], 0, 0, 0);
                sacc[nf] = __builtin_amdgcn_mfma_f32_16x16x32_bf16(qf1, kf1, sacc[nf], 0, 0, 0);
            }

            // ---- online softmax ----
            float p[4][4];
            #pragma unroll
            for (int r = 0; r < 4; ++r) {
                const int iq = q0 + l4 * 4 + r;
                float rmax = -1e30f;
                #pragma unroll
                for (int nf = 0; nf < 4; ++nf) {
                    const int diff = iq - (j0 + nf * 16 + l15);
                    const bool valid = (diff >= 0) && (diff <= window);
                    const float s = valid ? sacc[nf][r] * 0.125f : -1e30f;
                    p[r][nf] = s;
                    rmax = fmaxf(rmax, s);
                }
                rmax = fmaxf(rmax, __shfl_xor(rmax, 1));
                rmax = fmaxf(rmax, __shfl_xor(rmax, 2));
                rmax = fmaxf(rmax, __shfl_xor(rmax, 4));
                rmax = fmaxf(rmax, __shfl_xor(rmax, 8));
                const float mn = fmaxf(m[r], rmax);
                const float rf = __expf(m[r] - mn);
                float rs = 0.f;
                #pragma unroll
                for (int nf = 0; nf < 4; ++nf) {
                    const float e = __expf(p[r][nf] - mn);
                    p[r][nf] = e;
                    rs += e;
                }
                rs += __shfl_xor(rs, 1);
                rs += __shfl_xor(rs, 2);
                rs += __shfl_xor(rs, 4);
                rs += __shfl_xor(rs, 8);
                l[r] = l[r] * rf + rs;
                m[r] = mn;
                #pragma unroll
                for (int nf = 0; nf < 4; ++nf) oacc[nf][r] *= rf;
                #pragma unroll
                for (int nf = 0; nf < 4; ++nf)
                    Ps[swz(wave * 16 + l4 * 4 + r, nf * 16 + l15)] = (s16)f2bf(p[r][nf]);
            }
        }
        __syncthreads();                   // Ps visible (each wave reads own strip)

        if (active) {
            // ---- O += P @ V ----
            #pragma unroll
            for (int ks = 0; ks < 2; ++ks) {
                const bf16x8 pa = *reinterpret_cast<const bf16x8*>(&Ps[swz(wave * 16 + l15, ks * 32 + l4 * 8)]);
                #pragma unroll
                for (int nf = 0; nf < 4; ++nf) {
                    const bf16x8 vf = *reinterpret_cast<const bf16x8*>(&Vt[vtx(nf * 16 + l15, ks * 32 + l4 * 8)]);
                    oacc[nf] = __builtin_amdgcn_mfma_f32_16x16x32_bf16(pa, vf, oacc[nf], 0, 0, 0);
                }
            }
        }
    }

    // ---- epilogue: normalize, write bf16 ----
    #pragma unroll
    for (int r = 0; r < 4; ++r) {
        const float inv = 1.f / l[r];
        const size_t orow = (size_t)(b * T_SEQ + qt * 128 + wave * 16 + l4 * 4 + r) * DMODEL + hoff;
        #pragma unroll
        for (int nf = 0; nf < 4; ++nf)
            out[orow + nf * 16 + l15] = f2bf(oacc[nf][r] * inv);
    }
}

// ---------------------------------------------------------------------------
extern "C" void kernel_launch(void* const* d_in, const int* in_sizes, int n_in,
                              void* d_out, int out_size, void* d_ws, size_t ws_size,
                              hipStream_t stream) {
    (void)in_sizes; (void)n_in; (void)out_size; (void)ws_size;

    const float* x     = (const float*)d_in[0];   // [4096, 1024]
    const float* w_qkv = (const float*)d_in[1];   // [1024, 3072]
    const float* b_qkv = (const float*)d_in[2];   // [3072]
    const float* w_o   = (const float*)d_in[3];   // [1024, 1024]
    const float* b_o   = (const float*)d_in[4];   // [1024]
    const int*   wnd   = (const int*)d_in[5];

    const int M = 2 * T_SEQ;                      // 4096

    // ws layout (bytes): qkvb 24M | attb 8M | xb 8M | wqkvT 6M | woT 2M = 48 MB
    char* w = (char*)d_ws;
    u16* qkvb  = (u16*)(w);
    u16* attb  = (u16*)(w + 24u * 1024 * 1024);
    u16* xb    = (u16*)(w + 32u * 1024 * 1024);
    u16* wqkvT = (u16*)(w + 40u * 1024 * 1024);
    u16* woT   = (u16*)(w + 46u * 1024 * 1024);

    // 0) all converts in one launch
    prep_kernel<<<dim3(XCONV_BLOCKS + WQKV_BLOCKS + WO_BLOCKS), dim3(256), 0, stream>>>(
        x, xb, w_qkv, wqkvT, w_o, woT);

    // 1) qkv(bf16) = x @ w_qkv + b_qkv    (round-11 GEMM)
    gemm_mfma_kernel<128, 128, true><<<dim3(3 * DMODEL / 128, M / 128), dim3(256), 0, stream>>>(
        xb, wqkvT, b_qkv, nullptr, qkvb, M, 3 * DMODEL, DMODEL);

    // 2) banded attention (MFMA, QBLK=128, 8 waves)
    swa_mfma_kernel<<<dim3(T_SEQ / 128, 2 * NH), dim3(512), 0, stream>>>(qkvb, attb, wnd);

    // 3) out(fp32) = att @ w_o + b_o      (round-11 GEMM, BN=64)
    gemm_mfma_kernel<128, 64, false><<<dim3(DMODEL / 64, M / 128), dim3(256), 0, stream>>>(
        attb, woT, b_o, (float*)d_out, nullptr, M, DMODEL, DMODEL);
}